// Round 1
// baseline (50.433 us; speedup 1.0000x reference)
//
#include <hip/hip_runtime.h>

#define BUFF 10

constexpr int B = 8, N = 4096, H = 2048, W = 2048;
constexpr int WAVES_PER_BLOCK = 4;            // 256 threads = 4 waves, 1 point/wave
constexpr int NBLOCKS = (B * N) / WAVES_PER_BLOCK;  // 8192

__global__ __launch_bounds__(256) void score_windows(
    const float* __restrict__ scores, const float* __restrict__ points,
    const int* __restrict__ gt, const int* __restrict__ ps,
    float* __restrict__ out, float* __restrict__ partial)
{
    const int tid  = blockIdx.x * blockDim.x + threadIdx.x;
    const int idx  = tid >> 6;            // one wave per point, idx in [0, B*N)
    const int lane = threadIdx.x & 63;
    const int wid  = threadIdx.x >> 6;    // wave id within block (0..3)

    const int b = idx >> 12;              // idx / N  (N = 4096)

    // replicate JAX f32 arithmetic exactly: p=(v+1)/2; px=trunc(p*W)
    const float vx = points[2 * idx + 0];
    const float vy = points[2 * idx + 1];
    const int px = (int)(((vx + 1.0f) / 2.0f) * (float)W);
    const int py = (int)(((vy + 1.0f) / 2.0f) * (float)H);

    const int tx = min(max(px - BUFF, 0), W - 1);
    const int ty = min(max(py - BUFF, 0), H - 1);
    const int bx = min(max(px + BUFF, 0), W - 1);
    const int by = min(max(py + BUFF, 0), H - 1);

    const int ww = bx - tx;               // in [9, 20]
    const int hh = by - ty;
    const int total = ww * hh;            // <= 400, >= 81 (never 0)

    const int* __restrict__ gtb = gt + (size_t)b * (size_t)(H * W);
    const int* __restrict__ psb = ps + (size_t)b * (size_t)(H * W);

    int acc = 0;
    for (int i = lane; i < total; i += 64) {
        const int r = i / ww;
        const int c = i - r * ww;
        const int off = (ty + r) * W + (tx + c);
        acc += (gtb[off] == psb[off]) ? 1 : 0;
    }

    // 64-lane wave reduction
    #pragma unroll
    for (int o = 32; o > 0; o >>= 1) acc += __shfl_down(acc, o, 64);

    __shared__ float wsum[WAVES_PER_BLOCK];
    if (lane == 0) {
        // cnt/area: area == total (window pixel count), cnt in [0, total]
        const float sgt = fminf(fmaxf(fabsf((float)acc / (float)total), 0.0f), 1.0f);
        out[1 + idx] = sgt;
        const float d = scores[idx] - sgt;
        wsum[wid] = d * d;
    }
    __syncthreads();
    if (threadIdx.x == 0) {
        partial[blockIdx.x] = wsum[0] + wsum[1] + wsum[2] + wsum[3];
    }
}

__global__ __launch_bounds__(256) void loss_reduce(
    const float* __restrict__ partial, float* __restrict__ out, int nparts)
{
    __shared__ float sdata[256];
    float s = 0.0f;
    for (int i = threadIdx.x; i < nparts; i += 256) s += partial[i];  // fixed order
    sdata[threadIdx.x] = s;
    __syncthreads();
    #pragma unroll
    for (int k = 128; k > 0; k >>= 1) {
        if (threadIdx.x < k) sdata[threadIdx.x] += sdata[threadIdx.x + k];
        __syncthreads();
    }
    if (threadIdx.x == 0) out[0] = sdata[0] / (float)(B * N);
}

extern "C" void kernel_launch(void* const* d_in, const int* in_sizes, int n_in,
                              void* d_out, int out_size, void* d_ws, size_t ws_size,
                              hipStream_t stream) {
    const float* scores = (const float*)d_in[0];   // [B,N]
    const float* points = (const float*)d_in[1];   // [B,N,2]
    const int*   gt     = (const int*)d_in[2];     // [B,1,H,W]
    const int*   ps     = (const int*)d_in[3];     // [B,H,W]
    float* out     = (float*)d_out;                // [1 + B*N]
    float* partial = (float*)d_ws;                 // NBLOCKS floats (32 KB)

    score_windows<<<NBLOCKS, 256, 0, stream>>>(scores, points, gt, ps, out, partial);
    loss_reduce<<<1, 256, 0, stream>>>(partial, out, NBLOCKS);
}

// Round 2
// 44.927 us; speedup vs baseline: 1.1226x; 1.1226x over previous
//
#include <hip/hip_runtime.h>

#define BUFF 10

constexpr int B = 8, N = 4096, H = 2048, W = 2048;
constexpr int WAVES_PER_BLOCK = 4;            // 256 threads = 4 waves, 1 point/wave
constexpr int NBLOCKS = (B * N) / WAVES_PER_BLOCK;  // 8192
constexpr int KW = 21;                        // max window dim (2*BUFF+1)
constexpr int KCELLS = KW * KW;               // 441 padded cells
constexpr int KITER = (KCELLS + 63) / 64;     // 7 unrolled iterations

__global__ __launch_bounds__(256) void score_windows(
    const float* __restrict__ scores, const float* __restrict__ points,
    const int* __restrict__ gt, const int* __restrict__ ps,
    float* __restrict__ out, float* __restrict__ partial)
{
    const int tid  = blockIdx.x * blockDim.x + threadIdx.x;
    const int idx  = tid >> 6;            // one wave per point, idx in [0, B*N)
    const int lane = threadIdx.x & 63;
    const int wid  = threadIdx.x >> 6;    // wave id within block (0..3)

    const int b = idx >> 12;              // idx / N  (N = 4096)

    // replicate JAX f32 arithmetic exactly: p=(v+1)/2; px=trunc(p*W)
    const float vx = points[2 * idx + 0];
    const float vy = points[2 * idx + 1];
    const int px = (int)(((vx + 1.0f) / 2.0f) * (float)W);
    const int py = (int)(((vy + 1.0f) / 2.0f) * (float)H);

    const int tx = min(max(px - BUFF, 0), W - 1);
    const int ty = min(max(py - BUFF, 0), H - 1);
    const int bx = min(max(px + BUFF, 0), W - 1);
    const int by = min(max(py + BUFF, 0), H - 1);

    const int ww = bx - tx;               // in [9, 20]
    const int hh = by - ty;
    const int total = ww * hh;            // actual window area (<= 400)

    const int* __restrict__ gtb = gt + (size_t)b * (size_t)(H * W);
    const int* __restrict__ psb = ps + (size_t)b * (size_t)(H * W);

    // Walk a fixed 21x21 padded grid: compile-time /21 and %21 (magic mul),
    // full unroll -> all 14 loads issued before any waitcnt (max MLP).
    int acc = 0;
    #pragma unroll
    for (int k = 0; k < KITER; ++k) {
        const int i = lane + k * 64;              // 0..447
        const int r = i / KW;                     // const divide -> magic mul
        const int c = i - r * KW;
        const bool valid = (i < KCELLS) & (r < hh) & (c < ww);
        const int rr = min(r, hh - 1);            // safe in-window address
        const int cc = min(c, ww - 1);
        const int off = (ty + rr) * W + (tx + cc);
        const int g = gtb[off];
        const int p = psb[off];
        acc += (valid && (g == p)) ? 1 : 0;
    }

    // 64-lane wave reduction
    #pragma unroll
    for (int o = 32; o > 0; o >>= 1) acc += __shfl_down(acc, o, 64);

    __shared__ float wsum[WAVES_PER_BLOCK];
    if (lane == 0) {
        const float sgt = fminf(fmaxf(fabsf((float)acc / (float)total), 0.0f), 1.0f);
        out[1 + idx] = sgt;
        const float d = scores[idx] - sgt;
        wsum[wid] = d * d;
    }
    __syncthreads();
    if (threadIdx.x == 0) {
        partial[blockIdx.x] = wsum[0] + wsum[1] + wsum[2] + wsum[3];
    }
}

__global__ __launch_bounds__(1024) void loss_reduce(
    const float* __restrict__ partial, float* __restrict__ out, int nparts)
{
    __shared__ float sdata[1024];
    float s = 0.0f;
    for (int i = threadIdx.x; i < nparts; i += 1024) s += partial[i];  // fixed order
    sdata[threadIdx.x] = s;
    __syncthreads();
    #pragma unroll
    for (int k = 512; k > 0; k >>= 1) {
        if (threadIdx.x < k) sdata[threadIdx.x] += sdata[threadIdx.x + k];
        __syncthreads();
    }
    if (threadIdx.x == 0) out[0] = sdata[0] / (float)(B * N);
}

extern "C" void kernel_launch(void* const* d_in, const int* in_sizes, int n_in,
                              void* d_out, int out_size, void* d_ws, size_t ws_size,
                              hipStream_t stream) {
    const float* scores = (const float*)d_in[0];   // [B,N]
    const float* points = (const float*)d_in[1];   // [B,N,2]
    const int*   gt     = (const int*)d_in[2];     // [B,1,H,W]
    const int*   ps     = (const int*)d_in[3];     // [B,H,W]
    float* out     = (float*)d_out;                // [1 + B*N]
    float* partial = (float*)d_ws;                 // NBLOCKS floats (32 KB)

    score_windows<<<NBLOCKS, 256, 0, stream>>>(scores, points, gt, ps, out, partial);
    loss_reduce<<<1, 1024, 0, stream>>>(partial, out, NBLOCKS);
}